// Round 5
// baseline (486.610 us; speedup 1.0000x reference)
//
#include <hip/hip_runtime.h>

#define AANG 180
#define NN 256
#define BCH 12

#ifndef M_PI
#define M_PI 3.14159265358979323846
#endif

__device__ __forceinline__ int iclamp(int v, int lo, int hi) {
    return v < lo ? lo : (v > hi ? hi : v);
}

// ---------------- Radon v6: half-image LDS residency + wave-uniform u-trimming.
// Block = (n, half, angle-group); 1024 threads = 256 x-cols x 4 u-quarters.
// Per angle, each wave computes the analytic valid-u interval from its two
// extreme x values (endpoints linear in x), trims its 64-slot window to it,
// and keeps the per-sample predicate for boundary safety.
#define LSTR 259
#define LROWSMAX 130

__global__ __launch_bounds__(1024, 1)
void radon_kernel(const float* __restrict__ x, float* __restrict__ partial) {
    __shared__ float tile[LROWSMAX * LSTR];  // 134,680 B
    __shared__ float red[2][1024];           // + 8 KB (double-buffered)
    int blk = blockIdx.x;        // 12n x 2h x 32g
    int g = blk & 31;
    int h = (blk >> 5) & 1;
    int n = blk >> 6;
    int tid = threadIdx.x;
    int lx = tid & 255;   // output column
    int qid = tid >> 8;   // u-quarter
    int R0 = h ? 127 : -1;
    int nrows = h ? 130 : 129;
    float Ylo = h ? 127.0f : -1.0f;
    float Yhi = h ? 255.0f : 126.0f;
    float Yhi1 = Yhi + 1.0f;
    const float* img = x + (size_t)n * NN * NN;

    for (int rr = qid; rr < nrows; rr += 4) {
        int gr = R0 + rr;
        bool rok = (gr >= 0) && (gr < NN);
        const float* row = img + gr * NN;
        int gc = lx - 1;
        tile[rr * LSTR + lx] = (rok && gc >= 0) ? row[gc] : 0.0f;
        if (lx < 3) {
            int gc2 = 255 + lx;
            tile[rr * LSTR + 256 + lx] = (rok && gc2 < NN) ? row[gc2] : 0.0f;
        }
    }
    __syncthreads();

    float fx = (float)lx;
    int wave = tid >> 6;
    float fxA = (float)((wave & 3) * 64);  // wave's x extremes (within quarter)
    float fxB = fxA + 63.0f;
    int uq0 = qid * 64, uq1 = uq0 + 64;

    for (int aa = 0; aa < 6; ++aa) {
        int a = g + aa * 32;
        if (a >= AANG) break;
        float th = (float)((double)a * (M_PI / 180.0));
        float c = cosf(th), s = sinf(th);
        float kx = -128.0f * (c + s - 1.0f);
        float ky = -128.0f * (c - s - 1.0f);
        float xcon = c * fx + kx;   // sx = fma(s, fy, xcon)
        float dcon = -s * fx + ky;  // sy = fma(c, fy, dcon)

        // wave-uniform valid-u window (conservative)
        float loY, hiY;
        if (__builtin_fabsf(c) > 1e-5f) {
            float dA = -s * fxA + ky, dB = -s * fxB + ky;
            float t1 = (Ylo - dA) / c, t2 = (Yhi1 - dA) / c;
            float t3 = (Ylo - dB) / c, t4 = (Yhi1 - dB) / c;
            loY = fminf(fminf(t1, t2), fminf(t3, t4));
            hiY = fmaxf(fmaxf(t1, t2), fmaxf(t3, t4));
        } else { loY = 0.0f; hiY = 256.0f; }
        float loX, hiX;
        if (s > 1e-5f) {
            float xA = c * fxA + kx, xB = c * fxB + kx;
            float t1 = (-1.0f - xA) / s, t2 = (257.0f - xA) / s;
            float t3 = (-1.0f - xB) / s, t4 = (257.0f - xB) / s;
            loX = fminf(fminf(t1, t2), fminf(t3, t4));
            hiX = fmaxf(fmaxf(t1, t2), fmaxf(t3, t4));
        } else { loX = 0.0f; hiX = 256.0f; }
        float loF = fmaxf(fmaxf(loY, loX) - 1.0f, 0.0f);
        float hiF = fminf(fminf(hiY, hiX) + 2.0f, 256.0f);
        int us = max(uq0, (int)loF);
        int ue = min(uq1, (int)hiF);
        us = __builtin_amdgcn_readfirstlane(us);
        ue = __builtin_amdgcn_readfirstlane(ue);

        float acc = 0.0f;
        for (int u = us; u < ue; ++u) {
            float fy = (float)u;
            float sy = __builtin_fmaf(c, fy, dcon);
            float sx = __builtin_fmaf(s, fy, xcon);
            float iyf = floorf(sy), ixf = floorf(sx);
            if (iyf >= Ylo && iyf <= Yhi && ixf >= -1.0f && ixf <= 255.0f) {
                float wy = sy - iyf, wx = sx - ixf;
                int lr = (int)iyf - R0;
                int lc = (int)ixf + 1;
                const float* t0 = &tile[lr * LSTR + lc];
                float v00 = t0[0], v01 = t0[1];
                float v10 = t0[LSTR], v11 = t0[LSTR + 1];
                float wx1 = 1.0f - wx, wy1 = 1.0f - wy;
                acc += wy1 * (wx1 * v00 + wx * v01) + wy * (wx1 * v10 + wx * v11);
            }
        }
        int pb = aa & 1;
        red[pb][tid] = acc;
        __syncthreads();  // single barrier/angle: next angle uses other buffer
        if (tid < 256) {
            float ssum = red[pb][tid] + red[pb][tid + 256] + red[pb][tid + 512] +
                         red[pb][tid + 768];
            partial[(((size_t)h * BCH + n) * AANG + a) * NN + tid] = ssum;
        }
    }
}

// ---------------- W transpose (tiny). ----
__global__ void wtrans_kernel(const float* __restrict__ Wq, const float* __restrict__ Wk,
                              const float* __restrict__ Wv, float* __restrict__ WqT,
                              float* __restrict__ WkT, float* __restrict__ WvT) {
    int idx = blockIdx.x * 256 + threadIdx.x;
    if (idx < AANG * AANG) {
        int p = idx / AANG;
        int j = idx - p * AANG;
        int src = j * AANG + p;
        WqT[idx] = Wq[src];
        WkT[idx] = Wk[src];
        WvT[idx] = Wv[src];
    }
}

// ---------------- QKV: 256 threads, 8 rows/block. ----
__global__ void qkv_kernel(const float* __restrict__ partial,
                           const float* __restrict__ WqT, const float* __restrict__ bq,
                           const float* __restrict__ WkT, const float* __restrict__ bk,
                           const float* __restrict__ WvT, const float* __restrict__ bv,
                           float* __restrict__ Q, float* __restrict__ Kt,
                           float* __restrict__ V) {
    __shared__ float srow[8][AANG];
    int blk = blockIdx.x;  // n*32 + i8
    int n = blk >> 5;
    int i0 = (blk & 31) * 8;
    int tid = threadIdx.x;  // 256
    const size_t HOFF = (size_t)BCH * AANG * NN;
    if (tid < AANG) {
        for (int r = 0; r < 8; ++r) {
            size_t idx = (((size_t)n) * AANG + tid) * NN + (i0 + r);
            srow[r][tid] = partial[idx] + partial[idx + HOFF];
        }
    }
    __syncthreads();
    if (tid < AANG) {
        int j = tid;
        float aq[8], ak[8], av[8];
        float bqv = bq[j], bkv = bk[j], bvv = bv[j];
        for (int r = 0; r < 8; ++r) { aq[r] = bqv; ak[r] = bkv; av[r] = bvv; }
        for (int p = 0; p < AANG; ++p) {
            float wq = WqT[p * AANG + j];
            float wk = WkT[p * AANG + j];
            float wv = WvT[p * AANG + j];
#pragma unroll
            for (int r = 0; r < 8; ++r) {
                float sv = srow[r][p];
                aq[r] += sv * wq;
                ak[r] += sv * wk;
                av[r] += sv * wv;
            }
        }
        for (int r = 0; r < 8; ++r) {
            size_t qb = ((size_t)(n * NN + i0 + r)) * AANG + j;
            Q[qb] = aq[r];
            V[qb] = av[r];
        }
        size_t kb = ((size_t)(n * AANG + j)) * NN + i0;
        for (int r = 0; r < 8; ++r) Kt[kb + r] = ak[r];
    }
}

// ---------------- Attention: shfl wave reductions, 4 barriers total. ----
__global__ void attn_kernel(const float* __restrict__ Q, const float* __restrict__ Kt,
                            const float* __restrict__ V, float* __restrict__ att_t) {
    __shared__ float qrow0[AANG], qrow1[AANG];
    __shared__ float prob0[NN], prob1[NN];
    __shared__ float w0[4], w1[4];
    int blk = blockIdx.x;  // n*128 + i2
    int n = blk >> 7;
    int i0 = (blk & 127) * 2;
    int tid = threadIdx.x;  // 256: key index k
    int wid = tid >> 6;
    if (tid < AANG) {
        qrow0[tid] = Q[((size_t)(n * NN + i0)) * AANG + tid];
        qrow1[tid] = Q[((size_t)(n * NN + i0 + 1)) * AANG + tid];
    }
    __syncthreads();
    float dot0 = 0.0f, dot1 = 0.0f;
    for (int j = 0; j < AANG; ++j) {
        float kv = Kt[((size_t)(n * AANG + j)) * NN + tid];
        dot0 += qrow0[j] * kv;
        dot1 += qrow1[j] * kv;
    }
    const float rs = 0.0745355992f;  // 1/sqrt(180)
    float l0 = dot0 * rs, l1 = dot1 * rs;
    // wave max
    float m0 = l0, m1 = l1;
    for (int off = 32; off > 0; off >>= 1) {
        m0 = fmaxf(m0, __shfl_xor(m0, off));
        m1 = fmaxf(m1, __shfl_xor(m1, off));
    }
    if ((tid & 63) == 0) { w0[wid] = m0; w1[wid] = m1; }
    __syncthreads();
    float mx0 = fmaxf(fmaxf(w0[0], w0[1]), fmaxf(w0[2], w0[3]));
    float mx1 = fmaxf(fmaxf(w1[0], w1[1]), fmaxf(w1[2], w1[3]));
    float e0 = expf(l0 - mx0), e1 = expf(l1 - mx1);
    float s0 = e0, s1 = e1;
    for (int off = 32; off > 0; off >>= 1) {
        s0 += __shfl_xor(s0, off);
        s1 += __shfl_xor(s1, off);
    }
    __syncthreads();  // w0/w1 reads done before rewrite
    if ((tid & 63) == 0) { w0[wid] = s0; w1[wid] = s1; }
    __syncthreads();
    float d0 = w0[0] + w0[1] + w0[2] + w0[3];
    float d1 = w1[0] + w1[1] + w1[2] + w1[3];
    prob0[tid] = e0 / d0;
    prob1[tid] = e1 / d1;
    __syncthreads();
    if (tid < AANG) {
        float acc0 = 0.0f, acc1 = 0.0f;
        const float* vb = V + (size_t)n * NN * AANG + tid;
        for (int k = 0; k < NN; ++k) {
            float v = vb[(size_t)k * AANG];
            acc0 += prob0[k] * v;
            acc1 += prob1[k] * v;
        }
        size_t ob = ((size_t)(n * AANG + tid)) * NN + i0;
        att_t[ob] = acc0;
        att_t[ob + 1] = acc1;
    }
}

// ---------------- Ramp filter (128-tap symmetric conv). ----
__global__ void filter_kernel(const float* __restrict__ att_t, float* __restrict__ filt) {
    __shared__ float col[NN];
    __shared__ float coef[128];
    int blk = blockIdx.x;  // n*AANG + a
    int tid = threadIdx.x;
    col[tid] = att_t[(size_t)blk * NN + tid];
    if (tid < 128) {
        float d = (float)(2 * tid + 1);
        coef[tid] = -2.0f / ((float)(M_PI * M_PI) * d * d);
    }
    __syncthreads();
    float acc = 0.5f * col[tid];
    for (int m = 0; m < 128; ++m) {
        int d = 2 * m + 1;
        float lo = (tid - d >= 0) ? col[tid - d] : 0.0f;
        float hi = (tid + d < NN) ? col[tid + d] : 0.0f;
        acc += coef[m] * (lo + hi);
    }
    filt[(size_t)blk * NN + tid] = acc;
}

// ---------------- Backprojection: 12-angle LDS chunks. ----
#define ACH 12
__global__ void backproj_kernel(const float* __restrict__ filt, float* __restrict__ out) {
    __shared__ float cols[ACH][NN];
    __shared__ float cs[AANG], sn[AANG];
    int blk = blockIdx.x;  // n*NN + r
    int n = blk >> 8;
    int r = blk & 255;
    int tid = threadIdx.x;
    if (tid < AANG) {
        float th = (float)((double)tid * (M_PI / 180.0));
        cs[tid] = cosf(th);
        sn[tid] = sinf(th);
    }
    float xr = (float)(r - 128);
    float yr = (float)(tid - 128);
    float acc = 0.0f;
    const float* fb = filt + (size_t)n * AANG * NN;
    for (int ch = 0; ch < AANG / ACH; ++ch) {
        __syncthreads();
        for (int q = 0; q < ACH; ++q)
            cols[q][tid] = fb[(size_t)(ch * ACH + q) * NN + tid];
        __syncthreads();
        for (int q = 0; q < ACH; ++q) {
            int aa = ch * ACH + q;
            float t = yr * cs[aa] - xr * sn[aa] + 128.0f;
            float i0f = floorf(t);
            int i0 = (int)i0f;
            float frac = t - i0f;
            int c0 = iclamp(i0, 0, NN - 1);
            int c1 = iclamp(i0 + 1, 0, NN - 1);
            float val = (1.0f - frac) * cols[q][c0] + frac * cols[q][c1];
            if (t >= 0.0f && t <= 255.0f) acc += val;
        }
    }
    bool inside = (xr * xr + yr * yr) <= 16384.0f;
    out[(size_t)blk * NN + tid] = inside ? acc * (float)(M_PI / 360.0) : 0.0f;
}

extern "C" void kernel_launch(void* const* d_in, const int* in_sizes, int n_in,
                              void* d_out, int out_size, void* d_ws, size_t ws_size,
                              hipStream_t stream) {
    const float* x  = (const float*)d_in[0];
    const float* Wq = (const float*)d_in[1];
    const float* bq = (const float*)d_in[2];
    const float* Wk = (const float*)d_in[3];
    const float* bk = (const float*)d_in[4];
    const float* Wv = (const float*)d_in[5];
    const float* bv = (const float*)d_in[6];
    float* out = (float*)d_out;
    float* ws = (float*)d_ws;

    const size_t SZ = (size_t)BCH * NN * AANG;
    float* P     = ws;           // partial[2][n][a][x]
    float* Q     = P + 2 * SZ;
    float* Kt    = Q + SZ;
    float* V     = Kt + SZ;
    float* att_t = V + SZ;
    float* WqT   = att_t;        // alias: dead before attn writes att_t
    float* WkT   = WqT + AANG * AANG;
    float* WvT   = WkT + AANG * AANG;
    float* filt  = P;            // alias: partials dead after qkv

    wtrans_kernel<<<(AANG * AANG + 255) / 256, 256, 0, stream>>>(Wq, Wk, Wv, WqT, WkT, WvT);
    radon_kernel<<<BCH * 2 * 32, 1024, 0, stream>>>(x, P);
    qkv_kernel<<<BCH * (NN / 8), 256, 0, stream>>>(P, WqT, bq, WkT, bk, WvT, bv, Q, Kt, V);
    attn_kernel<<<BCH * (NN / 2), NN, 0, stream>>>(Q, Kt, V, att_t);
    filter_kernel<<<BCH * AANG, NN, 0, stream>>>(att_t, filt);
    backproj_kernel<<<BCH * NN, NN, 0, stream>>>(filt, out);
}